// Round 3
// baseline (311.413 us; speedup 1.0000x reference)
//
#include <hip/hip_runtime.h>
#include <hip/hip_bf16.h>
#include <math.h>

// B=2, N=2048, M=1024, H=16, DK=64. fp32 in/out.
// R17 = R16 + V-direct-to-register in attn_fast (LDS 40KB -> 24KB).
// R16 post-mortem: VALUBusy dropped 38->34.6 but dur_us unchanged ->
// latency-bound with only ~11 waves/CU (40KB LDS block caps residency at
// ~3 blocks/CU on the effective LDS budget). The lever is occupancy, not
// instruction count. V's LDS staging only existed to share 8KB among 4
// waves; the PV B-fragment is a clean per-lane 16B load from the V^T
// plane: vf[ks][ni] = V^T[d=ni*16+lm][k0+ks*32+quad*8 ..+7] (identical
// bytes to the old sw8 LDS read - derived from the staging algebra).
//   - LDS 24KB (K dbuf 16K + Psh 8K) -> >=4 blocks/CU resident, ~16 waves
//   - barrier drain is now 2 gll16 (K only); V/mask consumed pre-barrier
//   - V loads issue at tile start, latency covered by QK+exp phase
// Cost: 4x V read amplification (L2/L3-served; HBM at 14% has headroom),
// ~+32 VGPR (est ~115, under the __launch_bounds__(256,4) 128 cap).
// Precision plan (absmax 9.77e-4, stable since R7; numerics unchanged):
//   all projections 1-term | QK 2-term (ql = fp32-accumulator residue) | PV 1t
// 1/8 attention scale AND log2e folded into Wq/bq.

typedef __attribute__((ext_vector_type(8))) short bf16x8;
typedef __attribute__((ext_vector_type(4))) float f32x4;

typedef __attribute__((address_space(1))) void gvoid;   // global
typedef __attribute__((address_space(3))) void lvoid;   // LDS

// async 16B/lane global->LDS copy: 64 lanes -> 1KB at wave-uniform lds base
__device__ __forceinline__ void gll16(const void* g, void* l) {
    __builtin_amdgcn_global_load_lds(
        (gvoid*)(unsigned long long)g,
        (lvoid*)(unsigned int)(unsigned long long)l,   // low 32b = LDS offset
        16, 0, 0);
}

__device__ __forceinline__ short f2b(float f) {
    union { __hip_bfloat16 h; short s; } u;
    u.h = __float2bfloat16(f);   // RNE
    return u.s;
}
__device__ __forceinline__ float b2f(short s) {
    union { short s; __hip_bfloat16 h; } u;
    u.s = s;
    return __bfloat162float(u.h);
}

// XOR-swizzled element offset inside a [rows][64]-bf16 tile (16B blocks).
__device__ __forceinline__ int sw8(int r, int k8) {       // k8 = octet 0..7
    return (r << 6) + ((k8 ^ (r & 7)) << 3);
}
__device__ __forceinline__ int swe(int r, int k) {        // element-level
    return (r << 6) + (((k >> 3) ^ (r & 7)) << 3) + (k & 7);
}

// workspace layout (SHORT offsets). Every plane = 4194304 shorts (8 MB).
#define PLANE   4194304UL
#define OFF_WH  (0UL * PLANE)    // [4][1024][1024] W hi; Wq pre-scaled log2e/8
#define OFF_XH  (1UL * PLANE)    // [4096][1024] x hi
#define OFF_QH  (2UL * PLANE)    // [B,H,N,DK]
#define OFF_QL  (3UL * PLANE)
#define OFF_KH  (4UL * PLANE)    // hi only
#define OFF_VTH (5UL * PLANE)    // [B,H,DK,N] hi only
#define OFF_CH  (6UL * PLANE)    // [B,N,M] concat hi only

#define QSCALE  (0.125f * 1.44269504f)   // 1/8 attn scale * log2(e)

// ---------------------------------------------------------------------------
// Pre-split: W -> hi (Wq scaled by log2e/8); x -> hi only.
// ---------------------------------------------------------------------------
__global__ __launch_bounds__(256) void split_wx(
    const float* __restrict__ Wq, const float* __restrict__ Wk,
    const float* __restrict__ Wv, const float* __restrict__ Wo,
    const float* __restrict__ x,
    unsigned short* __restrict__ wh, unsigned short* __restrict__ xh)
{
    const int i = blockIdx.x * 256 + threadIdx.x;   // float4 idx, 2097152 total
    if (i < 1048576) {                               // weights
        const float* src = (i < 262144) ? Wq : (i < 524288) ? Wk
                         : (i < 786432) ? Wv : Wo;
        const float sc = (i < 262144) ? QSCALE : 1.0f;   // fold scale+log2e
        const int local = i & 262143;
        float4 v = ((const float4*)src)[local];
        short4 h;
        h.x = f2b(v.x * sc); h.y = f2b(v.y * sc);
        h.z = f2b(v.z * sc); h.w = f2b(v.w * sc);
        ((short4*)(wh + (size_t)(i >> 18) * 1048576))[local] = h;
    } else {                                         // x: hi only
        const int local = i - 1048576;
        float4 v = ((const float4*)x)[local];
        short4 h;
        h.x = f2b(v.x); h.y = f2b(v.y); h.z = f2b(v.z); h.w = f2b(v.w);
        ((short4*)xh)[local] = h;
    }
}

// ---------------------------------------------------------------------------
// Unified 1-term QKV GEMM (R13): ONE launch (8,32,3) = 768 blocks, LDS 32KB.
// z=0: Q -> hi/lo planes (lo = fp32-accumulator residue); z=1: K; z=2: V^T.
// ---------------------------------------------------------------------------
__global__ __launch_bounds__(256, 4) void gemm_qkv(
    unsigned short* __restrict__ wsS,
    const float* __restrict__ bq, const float* __restrict__ bk,
    const float* __restrict__ bv)
{
    __shared__ unsigned short Ash[128 * 64];
    __shared__ unsigned short Bsh[128 * 64];

    const int mode = blockIdx.z;                     // 0 Q, 1 K, 2 V
    const unsigned short* Ah = wsS + OFF_XH;
    const unsigned short* Wh = wsS + OFF_WH + (size_t)mode * 1048576;

    const int tid  = threadIdx.x;
    const int lane = tid & 63;
    const int lm   = lane & 15;
    const int quad = lane >> 4;
    const int w    = tid >> 6;
    const int wr   = w >> 1, wc = w & 1;

    const int row0 = blockIdx.y * 128;
    const int col0 = blockIdx.x * 128;

    const int srow = lane >> 3;
    const int soct = (lane & 7) ^ (srow & 7);

    f32x4 acc[4][4] = {};

    for (int k0 = 0; k0 < 1024; k0 += 64) {
        if (k0) __syncthreads();
        #pragma unroll
        for (int i = 0; i < 4; ++i) {
            const int rb = w * 32 + i * 8;           // wave-uniform row base
            gll16(&Ah[(size_t)(row0 + rb + srow) * 1024 + k0 + soct * 8],
                  &Ash[rb * 64]);
            gll16(&Wh[(size_t)(col0 + rb + srow) * 1024 + k0 + soct * 8],
                  &Bsh[rb * 64]);
        }
        __syncthreads();
        #pragma unroll
        for (int ks = 0; ks < 2; ++ks) {
            bf16x8 afh[4], bfh[4];
            #pragma unroll
            for (int mi = 0; mi < 4; ++mi)
                afh[mi] = *(const bf16x8*)&Ash[sw8(wr * 64 + mi * 16 + lm, ks * 4 + quad)];
            #pragma unroll
            for (int ni = 0; ni < 4; ++ni)
                bfh[ni] = *(const bf16x8*)&Bsh[sw8(wc * 64 + ni * 16 + lm, ks * 4 + quad)];
            #pragma unroll
            for (int mi = 0; mi < 4; ++mi) {
                #pragma unroll
                for (int ni = 0; ni < 4; ++ni)
                    acc[mi][ni] = __builtin_amdgcn_mfma_f32_16x16x32_bf16(
                        afh[mi], bfh[ni], acc[mi][ni], 0, 0, 0);
            }
        }
    }

    unsigned short* qh  = wsS + OFF_QH;
    unsigned short* ql  = wsS + OFF_QL;
    unsigned short* kh  = wsS + OFF_KH;
    unsigned short* vth = wsS + OFF_VTH;
    const float* bias = (mode == 0) ? bq : (mode == 1) ? bk : bv;
    const float bscale = (mode == 0) ? QSCALE : 1.0f;

    #pragma unroll
    for (int ni = 0; ni < 4; ++ni) {
        const int f = col0 + wc * 64 + ni * 16 + lm;
        const float bvv = bias[f] * bscale;
        const int h = f >> 6, d = f & 63;
        #pragma unroll
        for (int mi = 0; mi < 4; ++mi) {
            #pragma unroll
            for (int j = 0; j < 4; ++j) {
                const int row = row0 + wr * 64 + mi * 16 + quad * 4 + j;
                const float val = acc[mi][ni][j] + bvv;
                const int bb = row >> 11, n = row & 2047;
                const short hs = f2b(val);
                if (mode == 0) {
                    const size_t idx = ((size_t)(bb * 16 + h) * 2048 + n) * 64 + d;
                    qh[idx] = hs;
                    ql[idx] = f2b(val - b2f(hs));   // fp32-accumulator residue
                } else if (mode == 1) {
                    kh[((size_t)(bb * 16 + h) * 2048 + n) * 64 + d] = hs;
                } else {
                    vth[((size_t)(bb * 16 + h) * 64 + d) * 2048 + n] = hs;
                }
            }
        }
    }
}

// ---------------------------------------------------------------------------
// 1-term output projection, 512 threads / 8 waves (2 row-halves x 4 col-
// quarters): out = ch @ Wo^T + bo (fp32). Same 128x128 tile and LDS 32KB.
// ---------------------------------------------------------------------------
__global__ __launch_bounds__(512, 2) void gemm_out(
    const unsigned short* __restrict__ Ah,
    unsigned short* __restrict__ wsS,
    const float* __restrict__ bias_p, float* __restrict__ oout)
{
    __shared__ unsigned short Ash[128 * 64];
    __shared__ unsigned short Bsh[128 * 64];

    const unsigned short* Wh = wsS + OFF_WH + 3UL * 1048576;

    const int tid  = threadIdx.x;
    const int lane = tid & 63;
    const int lm   = lane & 15;
    const int quad = lane >> 4;
    const int w    = tid >> 6;          // 0..7
    const int wr   = w >> 2;            // 0..1  (64-row half)
    const int wc   = w & 3;             // 0..3  (32-col quarter)

    const int row0 = blockIdx.y * 128;
    const int col0 = blockIdx.x * 128;

    const int srow = lane >> 3;
    const int soct = (lane & 7) ^ (srow & 7);

    f32x4 acc[4][2] = {};

    for (int k0 = 0; k0 < 1024; k0 += 64) {
        if (k0) __syncthreads();
        #pragma unroll
        for (int i = 0; i < 2; ++i) {           // 8 waves x 2 x 1KB = 16KB each
            const int rb = w * 16 + i * 8;
            gll16(&Ah[(size_t)(row0 + rb + srow) * 1024 + k0 + soct * 8],
                  &Ash[rb * 64]);
            gll16(&Wh[(size_t)(col0 + rb + srow) * 1024 + k0 + soct * 8],
                  &Bsh[rb * 64]);
        }
        __syncthreads();
        #pragma unroll
        for (int ks = 0; ks < 2; ++ks) {
            bf16x8 afh[4], bfh[2];
            #pragma unroll
            for (int mi = 0; mi < 4; ++mi)
                afh[mi] = *(const bf16x8*)&Ash[sw8(wr * 64 + mi * 16 + lm, ks * 4 + quad)];
            #pragma unroll
            for (int ni = 0; ni < 2; ++ni)
                bfh[ni] = *(const bf16x8*)&Bsh[sw8(wc * 32 + ni * 16 + lm, ks * 4 + quad)];
            #pragma unroll
            for (int mi = 0; mi < 4; ++mi) {
                #pragma unroll
                for (int ni = 0; ni < 2; ++ni)
                    acc[mi][ni] = __builtin_amdgcn_mfma_f32_16x16x32_bf16(
                        afh[mi], bfh[ni], acc[mi][ni], 0, 0, 0);
            }
        }
    }

    #pragma unroll
    for (int ni = 0; ni < 2; ++ni) {
        const int f = col0 + wc * 32 + ni * 16 + lm;
        const float bvv = bias_p[f];
        #pragma unroll
        for (int mi = 0; mi < 4; ++mi) {
            #pragma unroll
            for (int j = 0; j < 4; ++j) {
                const int row = row0 + wr * 64 + mi * 16 + quad * 4 + j;
                oout[(size_t)row * 1024 + f] = acc[mi][ni][j] + bvv;
            }
        }
    }
}

// ---------------------------------------------------------------------------
// Flash attention (R17): 64 q-rows/block, deferred softmax, async K dbuf,
// V DIRECT TO REGISTERS, one barrier per K-tile. QK 2-term, PV 1-term.
// LDS 24KB (K dbuf 16K + Psh 8K) -> 4+ blocks/CU resident.
// ---------------------------------------------------------------------------
__global__ __launch_bounds__(256, 4) void attn_fast(
    const unsigned short* __restrict__ wsS, const float* __restrict__ mask,
    unsigned short* __restrict__ ch)
{
    __shared__ unsigned short Ksh[2][64 * 64];   // [buf][kcol][d] hi
    __shared__ unsigned short Psh[4][16 * 64];   // per-wave [q][k] hi

    const int tid  = threadIdx.x;
    const int lane = tid & 63;
    const int lm   = lane & 15;
    const int quad = lane >> 4;
    const int w    = tid >> 6;

    const int q0 = blockIdx.x * 64;
    const int h  = blockIdx.y;
    const int b  = blockIdx.z;
    const int bh = b * 16 + h;

    const unsigned short* Qhg = wsS + OFF_QH  + (size_t)bh * 2048 * 64;
    const unsigned short* Qlg = wsS + OFF_QL  + (size_t)bh * 2048 * 64;
    const unsigned short* Khg = wsS + OFF_KH  + (size_t)bh * 2048 * 64;
    const unsigned short* Vhg = wsS + OFF_VTH + (size_t)bh * 64 * 2048;

    // Q frags in registers (this wave's 16 q-rows); scale+log2e pre-folded
    bf16x8 qfh[2], qfl[2];
    #pragma unroll
    for (int ks = 0; ks < 2; ++ks) {
        const size_t qo = (size_t)(q0 + w * 16 + lm) * 64 + ks * 32 + quad * 8;
        qfh[ks] = *(const bf16x8*)&Qhg[qo];
        qfl[ks] = *(const bf16x8*)&Qlg[qo];
    }

    const int srow = lane >> 3;
    const int soct = (lane & 7) ^ (srow & 7);

    const int qwbase = q0 + w * 16 + quad * 4;
    // strength-reduced mask row pointers (advance 64 floats per tile)
    const float* mp0 = mask + (size_t)b * 2048 * 2048
                     + (size_t)(qwbase + 0) * 2048 + lm;
    const float* mp1 = mp0 + 2048;
    const float* mp2 = mp0 + 4096;
    const float* mp3 = mp0 + 6144;
    // V^T direct-load pointer: row d = ni*16+lm, octet quad (advances +64/tile)
    const unsigned short* vp = Vhg + (size_t)lm * 2048 + quad * 8;

    // prologue: async-load K tile 0 into buf 0
    #pragma unroll
    for (int i = 0; i < 2; ++i) {
        const int rb = w * 16 + i * 8;               // wave-uniform row base
        gll16(&Khg[(size_t)(rb + srow) * 64 + soct * 8], &Ksh[0][rb * 64]);
    }

    f32x4 o[4] = {};
    float lsum[4] = {0.f, 0.f, 0.f, 0.f};

    for (int t = 0; t < 32; ++t) {
        const int k0 = t * 64;
        const int p  = t & 1;

        __syncthreads();   // K tile t resident in buf p (prefetch had a tile)

        // mask loads first (oldest in vmcnt queue -> narrowest exp wait)
        float mr0[4], mr1[4], mr2[4], mr3[4];
        #pragma unroll
        for (int ni = 0; ni < 4; ++ni) {
            mr0[ni] = mp0[ni * 16];
            mr1[ni] = mp1[ni * 16];
            mr2[ni] = mp2[ni * 16];
            mr3[ni] = mp3[ni * 16];
        }
        mp0 += 64; mp1 += 64; mp2 += 64; mp3 += 64;

        // V direct loads for THIS tile (consumed at PV, a full QK+exp later).
        // vf[ks][ni] = V^T[d = ni*16+lm][k0 + ks*32 + quad*8 .. +7]
        bf16x8 vf[2][4];
        #pragma unroll
        for (int ks = 0; ks < 2; ++ks)
            #pragma unroll
            for (int ni = 0; ni < 4; ++ni)
                vf[ks][ni] = *(const bf16x8*)&vp[(size_t)ni * 32768 + ks * 32];
        vp += 64;

        // async-issue K tile t+1 into buf 1-p (lands before next barrier)
        if (t < 31) {
            #pragma unroll
            for (int i = 0; i < 2; ++i) {
                const int rb = w * 16 + i * 8;
                gll16(&Khg[(size_t)(k0 + 64 + rb + srow) * 64 + soct * 8],
                      &Ksh[1 - p][rb * 64]);
            }
        }

        // S' ~= (qh+ql) K_hi^T : 2 MFMA per (ks,ni); S' pre-scaled by log2e/8
        f32x4 s[4] = {};
        #pragma unroll
        for (int ks = 0; ks < 2; ++ks) {
            #pragma unroll
            for (int ni = 0; ni < 4; ++ni) {
                bf16x8 kh = *(const bf16x8*)&Ksh[p][sw8(ni * 16 + lm, ks * 4 + quad)];
                s[ni] = __builtin_amdgcn_mfma_f32_16x16x32_bf16(qfh[ks], kh, s[ni], 0, 0, 0);
                s[ni] = __builtin_amdgcn_mfma_f32_16x16x32_bf16(qfl[ks], kh, s[ni], 0, 0, 0);
            }
        }

        // p = exp2(s' * mask); per-lane partial row-sums; P(hi) -> own-wave LDS
        #pragma unroll
        for (int ni = 0; ni < 4; ++ni) {
            const float pv0 = __builtin_amdgcn_exp2f(s[ni][0] * mr0[ni]);
            const float pv1 = __builtin_amdgcn_exp2f(s[ni][1] * mr1[ni]);
            const float pv2 = __builtin_amdgcn_exp2f(s[ni][2] * mr2[ni]);
            const float pv3 = __builtin_amdgcn_exp2f(s[ni][3] * mr3[ni]);
            lsum[0] += pv0; lsum[1] += pv1; lsum[2] += pv2; lsum[3] += pv3;
            Psh[w][swe(quad * 4 + 0, ni * 16 + lm)] = f2b(pv0);
            Psh[w][swe(quad * 4 + 1, ni * 16 + lm)] = f2b(pv1);
            Psh[w][swe(quad * 4 + 2, ni * 16 + lm)] = f2b(pv2);
            Psh[w][swe(quad * 4 + 3, ni * 16 + lm)] = f2b(pv3);
        }

        // O += P_hi @ V_hi : V from registers (no LDS)
        #pragma unroll
        for (int ks = 0; ks < 2; ++ks) {
            bf16x8 ph = *(const bf16x8*)&Psh[w][sw8(lm, ks * 4 + quad)];
            #pragma unroll
            for (int ni = 0; ni < 4; ++ni)
                o[ni] = __builtin_amdgcn_mfma_f32_16x16x32_bf16(ph, vf[ks][ni], o[ni], 0, 0, 0);
        }
    }

    // epilogue: one cross-lane row-sum reduction, normalize, store concat hi
    #pragma unroll
    for (int j = 0; j < 4; ++j) {
        float ls = lsum[j];
        ls += __shfl_xor(ls, 1);
        ls += __shfl_xor(ls, 2);
        ls += __shfl_xor(ls, 4);
        ls += __shfl_xor(ls, 8);
        const float inv = 1.0f / ls;
        const int q = qwbase + j;
        #pragma unroll
        for (int ni = 0; ni < 4; ++ni)
            ch[((size_t)b * 2048 + q) * 1024 + h * 64 + ni * 16 + lm] =
                (unsigned short)f2b(o[ni][j] * inv);
    }
}

extern "C" void kernel_launch(void* const* d_in, const int* in_sizes, int n_in,
                              void* d_out, int out_size, void* d_ws, size_t ws_size,
                              hipStream_t stream) {
    const float* x    = (const float*)d_in[0];
    const float* mask = (const float*)d_in[1];
    const float* Wq   = (const float*)d_in[2];
    const float* bq   = (const float*)d_in[3];
    const float* Wk   = (const float*)d_in[4];
    const float* bk   = (const float*)d_in[5];
    const float* Wv   = (const float*)d_in[6];
    const float* bv   = (const float*)d_in[7];
    const float* Wo   = (const float*)d_in[8];
    const float* bo   = (const float*)d_in[9];

    unsigned short* wsS = (unsigned short*)d_ws;

    // 1. pre-split: W -> hi (Wq*log2e/8); x -> hi
    split_wx<<<8192, 256, 0, stream>>>(Wq, Wk, Wv, Wo, x,
        wsS + OFF_WH, wsS + OFF_XH);

    // 2. Q/K/V projections, ONE 768-block launch, all 1-term
    gemm_qkv<<<dim3(8, 32, 3), 256, 0, stream>>>(wsS, bq, bk, bv);

    // 3. flash attention (64-row, QK 2t / PV 1t, V-direct, LDS 24KB)
    attn_fast<<<dim3(32, 16, 2), 256, 0, stream>>>(wsS, mask, wsS + OFF_CH);

    // 4. output projection: 512 threads, 8 waves/CU
    gemm_out<<<dim3(8, 32), 512, 0, stream>>>(
        wsS + OFF_CH, wsS, bo, (float*)d_out);
}

// Round 4
// 249.467 us; speedup vs baseline: 1.2483x; 1.2483x over previous
//
#include <hip/hip_runtime.h>
#include <hip/hip_bf16.h>
#include <math.h>

// B=2, N=2048, M=1024, H=16, DK=64. fp32 in/out.
// R18 = R16 structure (V back in LDS — R17's V-direct regressed 87->158us:
// compiler sank the V global loads to the PV use site, exposing ~8 scattered
// ~400cy loads per tile; VGPR_Count=60 proved vf never stayed resident)
// + 512-thread / 8-wave / 128-q-row attention blocks:
//   - per-wave staging HALVES (1KB K + 1KB V per tile vs 2+2): tile shared
//     by 8 waves instead of 4
//   - LDS 48KB (K dbuf 16K + V dbuf 16K + Psh 16K); grid 16x16x2 = 512
//     blocks = 2/CU -> 16 waves/CU (50%) vs R16's measured 11 (34.6%)
//   - per-wave inner code byte-identical to R16 (w ranges 0..7, rb=w*8)
// Retained from R16: mask-first vmcnt ordering, exp2 with log2e pre-folded
// into Wq/bq, strength-reduced mask pointers.
// Precision plan (absmax 9.77e-4, stable since R7; numerics unchanged):
//   all projections 1-term | QK 2-term (ql = fp32-accumulator residue) | PV 1t
// 1/8 attention scale AND log2e folded into Wq/bq.

typedef __attribute__((ext_vector_type(8))) short bf16x8;
typedef __attribute__((ext_vector_type(4))) float f32x4;

typedef __attribute__((address_space(1))) void gvoid;   // global
typedef __attribute__((address_space(3))) void lvoid;   // LDS

// async 16B/lane global->LDS copy: 64 lanes -> 1KB at wave-uniform lds base
__device__ __forceinline__ void gll16(const void* g, void* l) {
    __builtin_amdgcn_global_load_lds(
        (gvoid*)(unsigned long long)g,
        (lvoid*)(unsigned int)(unsigned long long)l,   // low 32b = LDS offset
        16, 0, 0);
}

__device__ __forceinline__ short f2b(float f) {
    union { __hip_bfloat16 h; short s; } u;
    u.h = __float2bfloat16(f);   // RNE
    return u.s;
}
__device__ __forceinline__ float b2f(short s) {
    union { short s; __hip_bfloat16 h; } u;
    u.s = s;
    return __bfloat162float(u.h);
}

// XOR-swizzled element offset inside a [rows][64]-bf16 tile (16B blocks).
__device__ __forceinline__ int sw8(int r, int k8) {       // k8 = octet 0..7
    return (r << 6) + ((k8 ^ (r & 7)) << 3);
}
__device__ __forceinline__ int swe(int r, int k) {        // element-level
    return (r << 6) + (((k >> 3) ^ (r & 7)) << 3) + (k & 7);
}

// workspace layout (SHORT offsets). Every plane = 4194304 shorts (8 MB).
#define PLANE   4194304UL
#define OFF_WH  (0UL * PLANE)    // [4][1024][1024] W hi; Wq pre-scaled log2e/8
#define OFF_XH  (1UL * PLANE)    // [4096][1024] x hi
#define OFF_QH  (2UL * PLANE)    // [B,H,N,DK]
#define OFF_QL  (3UL * PLANE)
#define OFF_KH  (4UL * PLANE)    // hi only
#define OFF_VTH (5UL * PLANE)    // [B,H,DK,N] hi only
#define OFF_CH  (6UL * PLANE)    // [B,N,M] concat hi only

#define QSCALE  (0.125f * 1.44269504f)   // 1/8 attn scale * log2(e)

// ---------------------------------------------------------------------------
// Pre-split: W -> hi (Wq scaled by log2e/8); x -> hi only.
// ---------------------------------------------------------------------------
__global__ __launch_bounds__(256) void split_wx(
    const float* __restrict__ Wq, const float* __restrict__ Wk,
    const float* __restrict__ Wv, const float* __restrict__ Wo,
    const float* __restrict__ x,
    unsigned short* __restrict__ wh, unsigned short* __restrict__ xh)
{
    const int i = blockIdx.x * 256 + threadIdx.x;   // float4 idx, 2097152 total
    if (i < 1048576) {                               // weights
        const float* src = (i < 262144) ? Wq : (i < 524288) ? Wk
                         : (i < 786432) ? Wv : Wo;
        const float sc = (i < 262144) ? QSCALE : 1.0f;   // fold scale+log2e
        const int local = i & 262143;
        float4 v = ((const float4*)src)[local];
        short4 h;
        h.x = f2b(v.x * sc); h.y = f2b(v.y * sc);
        h.z = f2b(v.z * sc); h.w = f2b(v.w * sc);
        ((short4*)(wh + (size_t)(i >> 18) * 1048576))[local] = h;
    } else {                                         // x: hi only
        const int local = i - 1048576;
        float4 v = ((const float4*)x)[local];
        short4 h;
        h.x = f2b(v.x); h.y = f2b(v.y); h.z = f2b(v.z); h.w = f2b(v.w);
        ((short4*)xh)[local] = h;
    }
}

// ---------------------------------------------------------------------------
// Unified 1-term QKV GEMM (R13): ONE launch (8,32,3) = 768 blocks, LDS 32KB.
// z=0: Q -> hi/lo planes (lo = fp32-accumulator residue); z=1: K; z=2: V^T.
// ---------------------------------------------------------------------------
__global__ __launch_bounds__(256, 4) void gemm_qkv(
    unsigned short* __restrict__ wsS,
    const float* __restrict__ bq, const float* __restrict__ bk,
    const float* __restrict__ bv)
{
    __shared__ unsigned short Ash[128 * 64];
    __shared__ unsigned short Bsh[128 * 64];

    const int mode = blockIdx.z;                     // 0 Q, 1 K, 2 V
    const unsigned short* Ah = wsS + OFF_XH;
    const unsigned short* Wh = wsS + OFF_WH + (size_t)mode * 1048576;

    const int tid  = threadIdx.x;
    const int lane = tid & 63;
    const int lm   = lane & 15;
    const int quad = lane >> 4;
    const int w    = tid >> 6;
    const int wr   = w >> 1, wc = w & 1;

    const int row0 = blockIdx.y * 128;
    const int col0 = blockIdx.x * 128;

    const int srow = lane >> 3;
    const int soct = (lane & 7) ^ (srow & 7);

    f32x4 acc[4][4] = {};

    for (int k0 = 0; k0 < 1024; k0 += 64) {
        if (k0) __syncthreads();
        #pragma unroll
        for (int i = 0; i < 4; ++i) {
            const int rb = w * 32 + i * 8;           // wave-uniform row base
            gll16(&Ah[(size_t)(row0 + rb + srow) * 1024 + k0 + soct * 8],
                  &Ash[rb * 64]);
            gll16(&Wh[(size_t)(col0 + rb + srow) * 1024 + k0 + soct * 8],
                  &Bsh[rb * 64]);
        }
        __syncthreads();
        #pragma unroll
        for (int ks = 0; ks < 2; ++ks) {
            bf16x8 afh[4], bfh[4];
            #pragma unroll
            for (int mi = 0; mi < 4; ++mi)
                afh[mi] = *(const bf16x8*)&Ash[sw8(wr * 64 + mi * 16 + lm, ks * 4 + quad)];
            #pragma unroll
            for (int ni = 0; ni < 4; ++ni)
                bfh[ni] = *(const bf16x8*)&Bsh[sw8(wc * 64 + ni * 16 + lm, ks * 4 + quad)];
            #pragma unroll
            for (int mi = 0; mi < 4; ++mi) {
                #pragma unroll
                for (int ni = 0; ni < 4; ++ni)
                    acc[mi][ni] = __builtin_amdgcn_mfma_f32_16x16x32_bf16(
                        afh[mi], bfh[ni], acc[mi][ni], 0, 0, 0);
            }
        }
    }

    unsigned short* qh  = wsS + OFF_QH;
    unsigned short* ql  = wsS + OFF_QL;
    unsigned short* kh  = wsS + OFF_KH;
    unsigned short* vth = wsS + OFF_VTH;
    const float* bias = (mode == 0) ? bq : (mode == 1) ? bk : bv;
    const float bscale = (mode == 0) ? QSCALE : 1.0f;

    #pragma unroll
    for (int ni = 0; ni < 4; ++ni) {
        const int f = col0 + wc * 64 + ni * 16 + lm;
        const float bvv = bias[f] * bscale;
        const int h = f >> 6, d = f & 63;
        #pragma unroll
        for (int mi = 0; mi < 4; ++mi) {
            #pragma unroll
            for (int j = 0; j < 4; ++j) {
                const int row = row0 + wr * 64 + mi * 16 + quad * 4 + j;
                const float val = acc[mi][ni][j] + bvv;
                const int bb = row >> 11, n = row & 2047;
                const short hs = f2b(val);
                if (mode == 0) {
                    const size_t idx = ((size_t)(bb * 16 + h) * 2048 + n) * 64 + d;
                    qh[idx] = hs;
                    ql[idx] = f2b(val - b2f(hs));   // fp32-accumulator residue
                } else if (mode == 1) {
                    kh[((size_t)(bb * 16 + h) * 2048 + n) * 64 + d] = hs;
                } else {
                    vth[((size_t)(bb * 16 + h) * 64 + d) * 2048 + n] = hs;
                }
            }
        }
    }
}

// ---------------------------------------------------------------------------
// 1-term output projection, 512 threads / 8 waves (2 row-halves x 4 col-
// quarters): out = ch @ Wo^T + bo (fp32). Same 128x128 tile and LDS 32KB.
// ---------------------------------------------------------------------------
__global__ __launch_bounds__(512, 2) void gemm_out(
    const unsigned short* __restrict__ Ah,
    unsigned short* __restrict__ wsS,
    const float* __restrict__ bias_p, float* __restrict__ oout)
{
    __shared__ unsigned short Ash[128 * 64];
    __shared__ unsigned short Bsh[128 * 64];

    const unsigned short* Wh = wsS + OFF_WH + 3UL * 1048576;

    const int tid  = threadIdx.x;
    const int lane = tid & 63;
    const int lm   = lane & 15;
    const int quad = lane >> 4;
    const int w    = tid >> 6;          // 0..7
    const int wr   = w >> 2;            // 0..1  (64-row half)
    const int wc   = w & 3;             // 0..3  (32-col quarter)

    const int row0 = blockIdx.y * 128;
    const int col0 = blockIdx.x * 128;

    const int srow = lane >> 3;
    const int soct = (lane & 7) ^ (srow & 7);

    f32x4 acc[4][2] = {};

    for (int k0 = 0; k0 < 1024; k0 += 64) {
        if (k0) __syncthreads();
        #pragma unroll
        for (int i = 0; i < 2; ++i) {           // 8 waves x 2 x 1KB = 16KB each
            const int rb = w * 16 + i * 8;
            gll16(&Ah[(size_t)(row0 + rb + srow) * 1024 + k0 + soct * 8],
                  &Ash[rb * 64]);
            gll16(&Wh[(size_t)(col0 + rb + srow) * 1024 + k0 + soct * 8],
                  &Bsh[rb * 64]);
        }
        __syncthreads();
        #pragma unroll
        for (int ks = 0; ks < 2; ++ks) {
            bf16x8 afh[4], bfh[2];
            #pragma unroll
            for (int mi = 0; mi < 4; ++mi)
                afh[mi] = *(const bf16x8*)&Ash[sw8(wr * 64 + mi * 16 + lm, ks * 4 + quad)];
            #pragma unroll
            for (int ni = 0; ni < 2; ++ni)
                bfh[ni] = *(const bf16x8*)&Bsh[sw8(wc * 32 + ni * 16 + lm, ks * 4 + quad)];
            #pragma unroll
            for (int mi = 0; mi < 4; ++mi) {
                #pragma unroll
                for (int ni = 0; ni < 2; ++ni)
                    acc[mi][ni] = __builtin_amdgcn_mfma_f32_16x16x32_bf16(
                        afh[mi], bfh[ni], acc[mi][ni], 0, 0, 0);
            }
        }
    }

    #pragma unroll
    for (int ni = 0; ni < 2; ++ni) {
        const int f = col0 + wc * 32 + ni * 16 + lm;
        const float bvv = bias_p[f];
        #pragma unroll
        for (int mi = 0; mi < 4; ++mi) {
            #pragma unroll
            for (int j = 0; j < 4; ++j) {
                const int row = row0 + wr * 64 + mi * 16 + quad * 4 + j;
                oout[(size_t)row * 1024 + f] = acc[mi][ni][j] + bvv;
            }
        }
    }
}

// ---------------------------------------------------------------------------
// Flash attention (R18): 512 threads / 8 waves / 128 q-rows per block.
// Deferred softmax, async K/V dbuf, one barrier per K-tile. QK 2-term,
// PV 1-term. LDS 48KB (K 16K dbuf + V 16K dbuf + Psh 16K).
// Per-wave inner code identical to R16; staging per wave halved.
// ---------------------------------------------------------------------------
__global__ __launch_bounds__(512, 4) void attn_fast(
    const unsigned short* __restrict__ wsS, const float* __restrict__ mask,
    unsigned short* __restrict__ ch)
{
    __shared__ unsigned short Ksh[2][64 * 64];   // [buf][kcol][d] hi
    __shared__ unsigned short Vth[2][64 * 64];   // [buf][d][k]    hi
    __shared__ unsigned short Psh[8][16 * 64];   // per-wave [q][k] hi

    const int tid  = threadIdx.x;
    const int lane = tid & 63;
    const int lm   = lane & 15;
    const int quad = lane >> 4;
    const int w    = tid >> 6;                   // 0..7

    const int q0 = blockIdx.x * 128;
    const int h  = blockIdx.y;
    const int b  = blockIdx.z;
    const int bh = b * 16 + h;

    const unsigned short* Qhg = wsS + OFF_QH  + (size_t)bh * 2048 * 64;
    const unsigned short* Qlg = wsS + OFF_QL  + (size_t)bh * 2048 * 64;
    const unsigned short* Khg = wsS + OFF_KH  + (size_t)bh * 2048 * 64;
    const unsigned short* Vhg = wsS + OFF_VTH + (size_t)bh * 64 * 2048;

    // Q frags in registers (this wave's 16 q-rows); scale+log2e pre-folded
    bf16x8 qfh[2], qfl[2];
    #pragma unroll
    for (int ks = 0; ks < 2; ++ks) {
        const size_t qo = (size_t)(q0 + w * 16 + lm) * 64 + ks * 32 + quad * 8;
        qfh[ks] = *(const bf16x8*)&Qhg[qo];
        qfl[ks] = *(const bf16x8*)&Qlg[qo];
    }

    const int srow = lane >> 3;
    const int soct = (lane & 7) ^ (srow & 7);
    const int rb   = w * 8;                      // 8 rows per wave (8 waves)

    const int qwbase = q0 + w * 16 + quad * 4;
    // strength-reduced mask row pointers (advance 64 floats per tile)
    const float* mp0 = mask + (size_t)b * 2048 * 2048
                     + (size_t)(qwbase + 0) * 2048 + lm;
    const float* mp1 = mp0 + 2048;
    const float* mp2 = mp0 + 4096;
    const float* mp3 = mp0 + 6144;

    // prologue: async-load tile 0 into buf 0 (1KB K + 1KB V per wave)
    gll16(&Khg[(size_t)(rb + srow) * 64 + soct * 8],   &Ksh[0][rb * 64]);
    gll16(&Vhg[(size_t)(rb + srow) * 2048 + soct * 8], &Vth[0][rb * 64]);

    f32x4 o[4] = {};
    float lsum[4] = {0.f, 0.f, 0.f, 0.f};

    for (int t = 0; t < 32; ++t) {
        const int k0 = t * 64;
        const int p  = t & 1;

        __syncthreads();   // drains vmcnt -> tile t resident in buf p

        // mask loads FIRST: oldest in the in-order vmcnt queue, so the
        // pre-exp wait keeps the t+1 prefetch in flight.
        float mr0[4], mr1[4], mr2[4], mr3[4];
        #pragma unroll
        for (int ni = 0; ni < 4; ++ni) {
            mr0[ni] = mp0[ni * 16];
            mr1[ni] = mp1[ni * 16];
            mr2[ni] = mp2[ni * 16];
            mr3[ni] = mp3[ni * 16];
        }
        mp0 += 64; mp1 += 64; mp2 += 64; mp3 += 64;

        // async-issue tile t+1 into buf 1-p (lands before next barrier)
        if (t < 31) {
            gll16(&Khg[(size_t)(k0 + 64 + rb + srow) * 64 + soct * 8],
                  &Ksh[1 - p][rb * 64]);
            gll16(&Vhg[(size_t)(rb + srow) * 2048 + k0 + 64 + soct * 8],
                  &Vth[1 - p][rb * 64]);
        }

        // S' ~= (qh+ql) K_hi^T : 2 MFMA per (ks,ni); S' pre-scaled by log2e/8
        f32x4 s[4] = {};
        #pragma unroll
        for (int ks = 0; ks < 2; ++ks) {
            #pragma unroll
            for (int ni = 0; ni < 4; ++ni) {
                bf16x8 kh = *(const bf16x8*)&Ksh[p][sw8(ni * 16 + lm, ks * 4 + quad)];
                s[ni] = __builtin_amdgcn_mfma_f32_16x16x32_bf16(qfh[ks], kh, s[ni], 0, 0, 0);
                s[ni] = __builtin_amdgcn_mfma_f32_16x16x32_bf16(qfl[ks], kh, s[ni], 0, 0, 0);
            }
        }

        // p = exp2(s' * mask); per-lane partial row-sums; P(hi) -> own-wave LDS
        #pragma unroll
        for (int ni = 0; ni < 4; ++ni) {
            const float pv0 = __builtin_amdgcn_exp2f(s[ni][0] * mr0[ni]);
            const float pv1 = __builtin_amdgcn_exp2f(s[ni][1] * mr1[ni]);
            const float pv2 = __builtin_amdgcn_exp2f(s[ni][2] * mr2[ni]);
            const float pv3 = __builtin_amdgcn_exp2f(s[ni][3] * mr3[ni]);
            lsum[0] += pv0; lsum[1] += pv1; lsum[2] += pv2; lsum[3] += pv3;
            Psh[w][swe(quad * 4 + 0, ni * 16 + lm)] = f2b(pv0);
            Psh[w][swe(quad * 4 + 1, ni * 16 + lm)] = f2b(pv1);
            Psh[w][swe(quad * 4 + 2, ni * 16 + lm)] = f2b(pv2);
            Psh[w][swe(quad * 4 + 3, ni * 16 + lm)] = f2b(pv3);
        }

        // O += P_hi @ V_hi : 1 MFMA per (ks,ni)
        #pragma unroll
        for (int ks = 0; ks < 2; ++ks) {
            bf16x8 ph = *(const bf16x8*)&Psh[w][sw8(lm, ks * 4 + quad)];
            #pragma unroll
            for (int ni = 0; ni < 4; ++ni) {
                bf16x8 vh = *(const bf16x8*)&Vth[p][sw8(ni * 16 + lm, ks * 4 + quad)];
                o[ni] = __builtin_amdgcn_mfma_f32_16x16x32_bf16(ph, vh, o[ni], 0, 0, 0);
            }
        }
    }

    // epilogue: one cross-lane row-sum reduction, normalize, store concat hi
    #pragma unroll
    for (int j = 0; j < 4; ++j) {
        float ls = lsum[j];
        ls += __shfl_xor(ls, 1);
        ls += __shfl_xor(ls, 2);
        ls += __shfl_xor(ls, 4);
        ls += __shfl_xor(ls, 8);
        const float inv = 1.0f / ls;
        const int q = qwbase + j;
        #pragma unroll
        for (int ni = 0; ni < 4; ++ni)
            ch[((size_t)b * 2048 + q) * 1024 + h * 64 + ni * 16 + lm] =
                (unsigned short)f2b(o[ni][j] * inv);
    }
}

extern "C" void kernel_launch(void* const* d_in, const int* in_sizes, int n_in,
                              void* d_out, int out_size, void* d_ws, size_t ws_size,
                              hipStream_t stream) {
    const float* x    = (const float*)d_in[0];
    const float* mask = (const float*)d_in[1];
    const float* Wq   = (const float*)d_in[2];
    const float* bq   = (const float*)d_in[3];
    const float* Wk   = (const float*)d_in[4];
    const float* bk   = (const float*)d_in[5];
    const float* Wv   = (const float*)d_in[6];
    const float* bv   = (const float*)d_in[7];
    const float* Wo   = (const float*)d_in[8];
    const float* bo   = (const float*)d_in[9];

    unsigned short* wsS = (unsigned short*)d_ws;

    // 1. pre-split: W -> hi (Wq*log2e/8); x -> hi
    split_wx<<<8192, 256, 0, stream>>>(Wq, Wk, Wv, Wo, x,
        wsS + OFF_WH, wsS + OFF_XH);

    // 2. Q/K/V projections, ONE 768-block launch, all 1-term
    gemm_qkv<<<dim3(8, 32, 3), 256, 0, stream>>>(wsS, bq, bk, bv);

    // 3. flash attention: 512 threads, 128 q-rows/block, 512 blocks
    attn_fast<<<dim3(16, 16, 2), 512, 0, stream>>>(wsS, mask, wsS + OFF_CH);

    // 4. output projection: 512 threads, 8 waves/CU
    gemm_out<<<dim3(8, 32), 512, 0, stream>>>(
        wsS + OFF_CH, wsS, bo, (float*)d_out);
}

// Round 5
// 236.866 us; speedup vs baseline: 1.3147x; 1.0532x over previous
//
#include <hip/hip_runtime.h>
#include <hip/hip_bf16.h>
#include <math.h>

// B=2, N=2048, M=1024, H=16, DK=64. fp32 in/out.
// R19 = R18 + cross-tile software pipeline in attn_fast.
// R18 counters: MfmaUtil 25 = exactly (51.5 GFLOP @ peak = 20.7us)/85us;
// VALU 32; pipes sum ~60% -> ~40% of each tile is in-wave serial stall:
// mask-load latency + QK->exp dep + P ds_write->lgkmcnt(0)->ds_read gap,
// phase-locked across waves by the barrier. Restructured iteration t:
//   exp(s(t), mask(t))     <- both produced a full tile ago, zero stall
//   -> P writes -> stage K(t+2) -> QK(t+1) MFMAs (fill write->read gap)
//   -> PV(t) (lgkm wait ~free) -> rotate s/mask regs.
// Mask(t+1) preloads at top of t. Buffer audit: K dbuf (Ksh[p] written at
// t, last read pre-barrier t-1), V dbuf (Vth[1-p] written t, read t+1
// post-barrier), Psh single-buffer (same-wave in-order). T5 setprio(1)
// around both MFMA clusters (m191: +4-7% attn with phase diversity).
// LDS 48KB unchanged; VGPR ~110 under the (512,4) 128 cap.
// Precision plan (absmax 9.77e-4, stable since R7; numerics unchanged):
//   all projections 1-term | QK 2-term (ql = fp32-accumulator residue) | PV 1t
// 1/8 attention scale AND log2e folded into Wq/bq.

typedef __attribute__((ext_vector_type(8))) short bf16x8;
typedef __attribute__((ext_vector_type(4))) float f32x4;

typedef __attribute__((address_space(1))) void gvoid;   // global
typedef __attribute__((address_space(3))) void lvoid;   // LDS

// async 16B/lane global->LDS copy: 64 lanes -> 1KB at wave-uniform lds base
__device__ __forceinline__ void gll16(const void* g, void* l) {
    __builtin_amdgcn_global_load_lds(
        (gvoid*)(unsigned long long)g,
        (lvoid*)(unsigned int)(unsigned long long)l,   // low 32b = LDS offset
        16, 0, 0);
}

__device__ __forceinline__ short f2b(float f) {
    union { __hip_bfloat16 h; short s; } u;
    u.h = __float2bfloat16(f);   // RNE
    return u.s;
}
__device__ __forceinline__ float b2f(short s) {
    union { short s; __hip_bfloat16 h; } u;
    u.s = s;
    return __bfloat162float(u.h);
}

// XOR-swizzled element offset inside a [rows][64]-bf16 tile (16B blocks).
__device__ __forceinline__ int sw8(int r, int k8) {       // k8 = octet 0..7
    return (r << 6) + ((k8 ^ (r & 7)) << 3);
}
__device__ __forceinline__ int swe(int r, int k) {        // element-level
    return (r << 6) + (((k >> 3) ^ (r & 7)) << 3) + (k & 7);
}

// workspace layout (SHORT offsets). Every plane = 4194304 shorts (8 MB).
#define PLANE   4194304UL
#define OFF_WH  (0UL * PLANE)    // [4][1024][1024] W hi; Wq pre-scaled log2e/8
#define OFF_XH  (1UL * PLANE)    // [4096][1024] x hi
#define OFF_QH  (2UL * PLANE)    // [B,H,N,DK]
#define OFF_QL  (3UL * PLANE)
#define OFF_KH  (4UL * PLANE)    // hi only
#define OFF_VTH (5UL * PLANE)    // [B,H,DK,N] hi only
#define OFF_CH  (6UL * PLANE)    // [B,N,M] concat hi only

#define QSCALE  (0.125f * 1.44269504f)   // 1/8 attn scale * log2(e)

// ---------------------------------------------------------------------------
// Pre-split: W -> hi (Wq scaled by log2e/8); x -> hi only.
// ---------------------------------------------------------------------------
__global__ __launch_bounds__(256) void split_wx(
    const float* __restrict__ Wq, const float* __restrict__ Wk,
    const float* __restrict__ Wv, const float* __restrict__ Wo,
    const float* __restrict__ x,
    unsigned short* __restrict__ wh, unsigned short* __restrict__ xh)
{
    const int i = blockIdx.x * 256 + threadIdx.x;   // float4 idx, 2097152 total
    if (i < 1048576) {                               // weights
        const float* src = (i < 262144) ? Wq : (i < 524288) ? Wk
                         : (i < 786432) ? Wv : Wo;
        const float sc = (i < 262144) ? QSCALE : 1.0f;   // fold scale+log2e
        const int local = i & 262143;
        float4 v = ((const float4*)src)[local];
        short4 h;
        h.x = f2b(v.x * sc); h.y = f2b(v.y * sc);
        h.z = f2b(v.z * sc); h.w = f2b(v.w * sc);
        ((short4*)(wh + (size_t)(i >> 18) * 1048576))[local] = h;
    } else {                                         // x: hi only
        const int local = i - 1048576;
        float4 v = ((const float4*)x)[local];
        short4 h;
        h.x = f2b(v.x); h.y = f2b(v.y); h.z = f2b(v.z); h.w = f2b(v.w);
        ((short4*)xh)[local] = h;
    }
}

// ---------------------------------------------------------------------------
// Unified 1-term QKV GEMM (R13): ONE launch (8,32,3) = 768 blocks, LDS 32KB.
// z=0: Q -> hi/lo planes (lo = fp32-accumulator residue); z=1: K; z=2: V^T.
// ---------------------------------------------------------------------------
__global__ __launch_bounds__(256, 4) void gemm_qkv(
    unsigned short* __restrict__ wsS,
    const float* __restrict__ bq, const float* __restrict__ bk,
    const float* __restrict__ bv)
{
    __shared__ unsigned short Ash[128 * 64];
    __shared__ unsigned short Bsh[128 * 64];

    const int mode = blockIdx.z;                     // 0 Q, 1 K, 2 V
    const unsigned short* Ah = wsS + OFF_XH;
    const unsigned short* Wh = wsS + OFF_WH + (size_t)mode * 1048576;

    const int tid  = threadIdx.x;
    const int lane = tid & 63;
    const int lm   = lane & 15;
    const int quad = lane >> 4;
    const int w    = tid >> 6;
    const int wr   = w >> 1, wc = w & 1;

    const int row0 = blockIdx.y * 128;
    const int col0 = blockIdx.x * 128;

    const int srow = lane >> 3;
    const int soct = (lane & 7) ^ (srow & 7);

    f32x4 acc[4][4] = {};

    for (int k0 = 0; k0 < 1024; k0 += 64) {
        if (k0) __syncthreads();
        #pragma unroll
        for (int i = 0; i < 4; ++i) {
            const int rb = w * 32 + i * 8;           // wave-uniform row base
            gll16(&Ah[(size_t)(row0 + rb + srow) * 1024 + k0 + soct * 8],
                  &Ash[rb * 64]);
            gll16(&Wh[(size_t)(col0 + rb + srow) * 1024 + k0 + soct * 8],
                  &Bsh[rb * 64]);
        }
        __syncthreads();
        #pragma unroll
        for (int ks = 0; ks < 2; ++ks) {
            bf16x8 afh[4], bfh[4];
            #pragma unroll
            for (int mi = 0; mi < 4; ++mi)
                afh[mi] = *(const bf16x8*)&Ash[sw8(wr * 64 + mi * 16 + lm, ks * 4 + quad)];
            #pragma unroll
            for (int ni = 0; ni < 4; ++ni)
                bfh[ni] = *(const bf16x8*)&Bsh[sw8(wc * 64 + ni * 16 + lm, ks * 4 + quad)];
            #pragma unroll
            for (int mi = 0; mi < 4; ++mi) {
                #pragma unroll
                for (int ni = 0; ni < 4; ++ni)
                    acc[mi][ni] = __builtin_amdgcn_mfma_f32_16x16x32_bf16(
                        afh[mi], bfh[ni], acc[mi][ni], 0, 0, 0);
            }
        }
    }

    unsigned short* qh  = wsS + OFF_QH;
    unsigned short* ql  = wsS + OFF_QL;
    unsigned short* kh  = wsS + OFF_KH;
    unsigned short* vth = wsS + OFF_VTH;
    const float* bias = (mode == 0) ? bq : (mode == 1) ? bk : bv;
    const float bscale = (mode == 0) ? QSCALE : 1.0f;

    #pragma unroll
    for (int ni = 0; ni < 4; ++ni) {
        const int f = col0 + wc * 64 + ni * 16 + lm;
        const float bvv = bias[f] * bscale;
        const int h = f >> 6, d = f & 63;
        #pragma unroll
        for (int mi = 0; mi < 4; ++mi) {
            #pragma unroll
            for (int j = 0; j < 4; ++j) {
                const int row = row0 + wr * 64 + mi * 16 + quad * 4 + j;
                const float val = acc[mi][ni][j] + bvv;
                const int bb = row >> 11, n = row & 2047;
                const short hs = f2b(val);
                if (mode == 0) {
                    const size_t idx = ((size_t)(bb * 16 + h) * 2048 + n) * 64 + d;
                    qh[idx] = hs;
                    ql[idx] = f2b(val - b2f(hs));   // fp32-accumulator residue
                } else if (mode == 1) {
                    kh[((size_t)(bb * 16 + h) * 2048 + n) * 64 + d] = hs;
                } else {
                    vth[((size_t)(bb * 16 + h) * 64 + d) * 2048 + n] = hs;
                }
            }
        }
    }
}

// ---------------------------------------------------------------------------
// 1-term output projection, 512 threads / 8 waves (2 row-halves x 4 col-
// quarters): out = ch @ Wo^T + bo (fp32). Same 128x128 tile and LDS 32KB.
// ---------------------------------------------------------------------------
__global__ __launch_bounds__(512, 2) void gemm_out(
    const unsigned short* __restrict__ Ah,
    unsigned short* __restrict__ wsS,
    const float* __restrict__ bias_p, float* __restrict__ oout)
{
    __shared__ unsigned short Ash[128 * 64];
    __shared__ unsigned short Bsh[128 * 64];

    const unsigned short* Wh = wsS + OFF_WH + 3UL * 1048576;

    const int tid  = threadIdx.x;
    const int lane = tid & 63;
    const int lm   = lane & 15;
    const int quad = lane >> 4;
    const int w    = tid >> 6;          // 0..7
    const int wr   = w >> 2;            // 0..1  (64-row half)
    const int wc   = w & 3;             // 0..3  (32-col quarter)

    const int row0 = blockIdx.y * 128;
    const int col0 = blockIdx.x * 128;

    const int srow = lane >> 3;
    const int soct = (lane & 7) ^ (srow & 7);

    f32x4 acc[4][2] = {};

    for (int k0 = 0; k0 < 1024; k0 += 64) {
        if (k0) __syncthreads();
        #pragma unroll
        for (int i = 0; i < 2; ++i) {           // 8 waves x 2 x 1KB = 16KB each
            const int rb = w * 16 + i * 8;
            gll16(&Ah[(size_t)(row0 + rb + srow) * 1024 + k0 + soct * 8],
                  &Ash[rb * 64]);
            gll16(&Wh[(size_t)(col0 + rb + srow) * 1024 + k0 + soct * 8],
                  &Bsh[rb * 64]);
        }
        __syncthreads();
        #pragma unroll
        for (int ks = 0; ks < 2; ++ks) {
            bf16x8 afh[4], bfh[2];
            #pragma unroll
            for (int mi = 0; mi < 4; ++mi)
                afh[mi] = *(const bf16x8*)&Ash[sw8(wr * 64 + mi * 16 + lm, ks * 4 + quad)];
            #pragma unroll
            for (int ni = 0; ni < 2; ++ni)
                bfh[ni] = *(const bf16x8*)&Bsh[sw8(wc * 32 + ni * 16 + lm, ks * 4 + quad)];
            #pragma unroll
            for (int mi = 0; mi < 4; ++mi) {
                #pragma unroll
                for (int ni = 0; ni < 2; ++ni)
                    acc[mi][ni] = __builtin_amdgcn_mfma_f32_16x16x32_bf16(
                        afh[mi], bfh[ni], acc[mi][ni], 0, 0, 0);
            }
        }
    }

    #pragma unroll
    for (int ni = 0; ni < 2; ++ni) {
        const int f = col0 + wc * 32 + ni * 16 + lm;
        const float bvv = bias_p[f];
        #pragma unroll
        for (int mi = 0; mi < 4; ++mi) {
            #pragma unroll
            for (int j = 0; j < 4; ++j) {
                const int row = row0 + wr * 64 + mi * 16 + quad * 4 + j;
                oout[(size_t)row * 1024 + f] = acc[mi][ni][j] + bvv;
            }
        }
    }
}

// ---------------------------------------------------------------------------
// Flash attention (R19): 512 threads / 8 waves / 128 q-rows per block.
// CROSS-TILE PIPELINE: iteration t does exp/P-write for tile t (s carried
// in regs from last iter), QK for t+1, PV for t. Mask preloads one tile
// ahead. K/V dbuf in LDS, Psh single-buffer (same-wave in-order).
// QK 2-term, PV 1-term. LDS 48KB. setprio(1) around MFMA clusters.
// ---------------------------------------------------------------------------
__global__ __launch_bounds__(512, 4) void attn_fast(
    const unsigned short* __restrict__ wsS, const float* __restrict__ mask,
    unsigned short* __restrict__ ch)
{
    __shared__ unsigned short Ksh[2][64 * 64];   // [buf][kcol][d] hi
    __shared__ unsigned short Vth[2][64 * 64];   // [buf][d][k]    hi
    __shared__ unsigned short Psh[8][16 * 64];   // per-wave [q][k] hi

    const int tid  = threadIdx.x;
    const int lane = tid & 63;
    const int lm   = lane & 15;
    const int quad = lane >> 4;
    const int w    = tid >> 6;                   // 0..7

    const int q0 = blockIdx.x * 128;
    const int h  = blockIdx.y;
    const int b  = blockIdx.z;
    const int bh = b * 16 + h;

    const unsigned short* Qhg = wsS + OFF_QH  + (size_t)bh * 2048 * 64;
    const unsigned short* Qlg = wsS + OFF_QL  + (size_t)bh * 2048 * 64;
    const unsigned short* Khg = wsS + OFF_KH  + (size_t)bh * 2048 * 64;
    const unsigned short* Vhg = wsS + OFF_VTH + (size_t)bh * 64 * 2048;

    // Q frags in registers (this wave's 16 q-rows); scale+log2e pre-folded
    bf16x8 qfh[2], qfl[2];
    #pragma unroll
    for (int ks = 0; ks < 2; ++ks) {
        const size_t qo = (size_t)(q0 + w * 16 + lm) * 64 + ks * 32 + quad * 8;
        qfh[ks] = *(const bf16x8*)&Qhg[qo];
        qfl[ks] = *(const bf16x8*)&Qlg[qo];
    }

    const int srow = lane >> 3;
    const int soct = (lane & 7) ^ (srow & 7);
    const int rb   = w * 8;                      // 8 rows per wave (8 waves)

    const int qwbase = q0 + w * 16 + quad * 4;
    // strength-reduced mask row pointers (advance 64 floats per tile)
    const float* mp0 = mask + (size_t)b * 2048 * 2048
                     + (size_t)(qwbase + 0) * 2048 + lm;
    const float* mp1 = mp0 + 2048;
    const float* mp2 = mp0 + 4096;
    const float* mp3 = mp0 + 6144;

    // prologue: stage K(0),V(0),K(1); preload mask(0); barrier; QK(0)
    gll16(&Khg[(size_t)(rb + srow) * 64 + soct * 8],        &Ksh[0][rb * 64]);
    gll16(&Vhg[(size_t)(rb + srow) * 2048 + soct * 8],      &Vth[0][rb * 64]);
    gll16(&Khg[(size_t)(64 + rb + srow) * 64 + soct * 8],   &Ksh[1][rb * 64]);

    float mc0[4], mc1[4], mc2[4], mc3[4];
    #pragma unroll
    for (int ni = 0; ni < 4; ++ni) {
        mc0[ni] = mp0[ni * 16];
        mc1[ni] = mp1[ni * 16];
        mc2[ni] = mp2[ni * 16];
        mc3[ni] = mp3[ni * 16];
    }
    mp0 += 64; mp1 += 64; mp2 += 64; mp3 += 64;

    __syncthreads();   // K(0), V(0) resident

    f32x4 scur[4] = {};
    __builtin_amdgcn_s_setprio(1);
    #pragma unroll
    for (int ks = 0; ks < 2; ++ks) {
        #pragma unroll
        for (int ni = 0; ni < 4; ++ni) {
            bf16x8 kh = *(const bf16x8*)&Ksh[0][sw8(ni * 16 + lm, ks * 4 + quad)];
            scur[ni] = __builtin_amdgcn_mfma_f32_16x16x32_bf16(qfh[ks], kh, scur[ni], 0, 0, 0);
            scur[ni] = __builtin_amdgcn_mfma_f32_16x16x32_bf16(qfl[ks], kh, scur[ni], 0, 0, 0);
        }
    }
    __builtin_amdgcn_s_setprio(0);

    f32x4 o[4] = {};
    float lsum[4] = {0.f, 0.f, 0.f, 0.f};

    for (int t = 0; t < 32; ++t) {
        const int p = t & 1;

        __syncthreads();   // K(t+1) in Ksh[1-p], V(t) in Vth[p] resident

        // mask(t+1) preload + V(t+1) stage (into Vth[1-p]; its last reads
        // were PV(t-1), pre-barrier)
        float mn0[4], mn1[4], mn2[4], mn3[4];
        if (t < 31) {
            #pragma unroll
            for (int ni = 0; ni < 4; ++ni) {
                mn0[ni] = mp0[ni * 16];
                mn1[ni] = mp1[ni * 16];
                mn2[ni] = mp2[ni * 16];
                mn3[ni] = mp3[ni * 16];
            }
            mp0 += 64; mp1 += 64; mp2 += 64; mp3 += 64;
            gll16(&Vhg[(size_t)(rb + srow) * 2048 + (t + 1) * 64 + soct * 8],
                  &Vth[1 - p][rb * 64]);
        }

        // exp(tile t): s and mask both a full tile old — zero stall
        #pragma unroll
        for (int ni = 0; ni < 4; ++ni) {
            const float pv0 = __builtin_amdgcn_exp2f(scur[ni][0] * mc0[ni]);
            const float pv1 = __builtin_amdgcn_exp2f(scur[ni][1] * mc1[ni]);
            const float pv2 = __builtin_amdgcn_exp2f(scur[ni][2] * mc2[ni]);
            const float pv3 = __builtin_amdgcn_exp2f(scur[ni][3] * mc3[ni]);
            lsum[0] += pv0; lsum[1] += pv1; lsum[2] += pv2; lsum[3] += pv3;
            Psh[w][swe(quad * 4 + 0, ni * 16 + lm)] = f2b(pv0);
            Psh[w][swe(quad * 4 + 1, ni * 16 + lm)] = f2b(pv1);
            Psh[w][swe(quad * 4 + 2, ni * 16 + lm)] = f2b(pv2);
            Psh[w][swe(quad * 4 + 3, ni * 16 + lm)] = f2b(pv3);
        }

        // stage K(t+2) into Ksh[p] (last read by QK(t), pre-barrier)
        if (t < 30)
            gll16(&Khg[(size_t)((t + 2) * 64 + rb + srow) * 64 + soct * 8],
                  &Ksh[p][rb * 64]);

        // QK(t+1) from Ksh[1-p] — fills the P write->read gap with MFMAs
        f32x4 snew[4] = {};
        if (t < 31) {
            __builtin_amdgcn_s_setprio(1);
            #pragma unroll
            for (int ks = 0; ks < 2; ++ks) {
                #pragma unroll
                for (int ni = 0; ni < 4; ++ni) {
                    bf16x8 kh = *(const bf16x8*)&Ksh[1 - p][sw8(ni * 16 + lm, ks * 4 + quad)];
                    snew[ni] = __builtin_amdgcn_mfma_f32_16x16x32_bf16(qfh[ks], kh, snew[ni], 0, 0, 0);
                    snew[ni] = __builtin_amdgcn_mfma_f32_16x16x32_bf16(qfl[ks], kh, snew[ni], 0, 0, 0);
                }
            }
            __builtin_amdgcn_s_setprio(0);
        }

        // PV(t): P round-trip latency covered by QK(t+1) above
        __builtin_amdgcn_s_setprio(1);
        #pragma unroll
        for (int ks = 0; ks < 2; ++ks) {
            bf16x8 ph = *(const bf16x8*)&Psh[w][sw8(lm, ks * 4 + quad)];
            #pragma unroll
            for (int ni = 0; ni < 4; ++ni) {
                bf16x8 vh = *(const bf16x8*)&Vth[p][sw8(ni * 16 + lm, ks * 4 + quad)];
                o[ni] = __builtin_amdgcn_mfma_f32_16x16x32_bf16(ph, vh, o[ni], 0, 0, 0);
            }
        }
        __builtin_amdgcn_s_setprio(0);

        // rotate carried registers
        if (t < 31) {
            #pragma unroll
            for (int ni = 0; ni < 4; ++ni) {
                scur[ni] = snew[ni];
                mc0[ni] = mn0[ni]; mc1[ni] = mn1[ni];
                mc2[ni] = mn2[ni]; mc3[ni] = mn3[ni];
            }
        }
    }

    // epilogue: one cross-lane row-sum reduction, normalize, store concat hi
    #pragma unroll
    for (int j = 0; j < 4; ++j) {
        float ls = lsum[j];
        ls += __shfl_xor(ls, 1);
        ls += __shfl_xor(ls, 2);
        ls += __shfl_xor(ls, 4);
        ls += __shfl_xor(ls, 8);
        const float inv = 1.0f / ls;
        const int q = qwbase + j;
        #pragma unroll
        for (int ni = 0; ni < 4; ++ni)
            ch[((size_t)b * 2048 + q) * 1024 + h * 64 + ni * 16 + lm] =
                (unsigned short)f2b(o[ni][j] * inv);
    }
}

extern "C" void kernel_launch(void* const* d_in, const int* in_sizes, int n_in,
                              void* d_out, int out_size, void* d_ws, size_t ws_size,
                              hipStream_t stream) {
    const float* x    = (const float*)d_in[0];
    const float* mask = (const float*)d_in[1];
    const float* Wq   = (const float*)d_in[2];
    const float* bq   = (const float*)d_in[3];
    const float* Wk   = (const float*)d_in[4];
    const float* bk   = (const float*)d_in[5];
    const float* Wv   = (const float*)d_in[6];
    const float* bv   = (const float*)d_in[7];
    const float* Wo   = (const float*)d_in[8];
    const float* bo   = (const float*)d_in[9];

    unsigned short* wsS = (unsigned short*)d_ws;

    // 1. pre-split: W -> hi (Wq*log2e/8); x -> hi
    split_wx<<<8192, 256, 0, stream>>>(Wq, Wk, Wv, Wo, x,
        wsS + OFF_WH, wsS + OFF_XH);

    // 2. Q/K/V projections, ONE 768-block launch, all 1-term
    gemm_qkv<<<dim3(8, 32, 3), 256, 0, stream>>>(wsS, bq, bk, bv);

    // 3. flash attention: 512 threads, 128 q-rows/block, cross-tile pipeline
    attn_fast<<<dim3(16, 16, 2), 512, 0, stream>>>(wsS, mask, wsS + OFF_CH);

    // 4. output projection: 512 threads, 8 waves/CU
    gemm_out<<<dim3(8, 32), 512, 0, stream>>>(
        wsS + OFF_CH, wsS, bo, (float*)d_out);
}